// Round 2
// baseline (122.569 us; speedup 1.0000x reference)
//
#include <hip/hip_runtime.h>

#define N_IN  1024
#define N_OUT 512
#define BATCH 128

// tiling
#define JT 64      // j columns per block (one per lane)
#define BT 32      // batches per block
#define BB 8       // batch accumulators per thread (BT = 4 waves * BB)
#define CH 65      // i rows per chunk (16 chunks cover 1025)
#define J_TILES  (N_OUT / JT)    // 8
#define B_TILES  (BATCH / BT)    // 4
#define I_CHUNKS 16

// fast base-2 transcendentals: v_exp_f32 / v_log_f32 (both base-2 on AMDGPU)
#if defined(__has_builtin)
#  if __has_builtin(__builtin_amdgcn_exp2f)
#    define FAST_EXP2(x) __builtin_amdgcn_exp2f(x)
#  endif
#  if __has_builtin(__builtin_amdgcn_logf)
#    define FAST_LOG2(x) __builtin_amdgcn_logf(x)
#  endif
#endif
#ifndef FAST_EXP2
#  define FAST_EXP2(x) exp2f(x)
#endif
#ifndef FAST_LOG2
#  define FAST_LOG2(x) log2f(x)
#endif

// ---------------------------------------------------------------------------
// Kernel 1: max(|combined weights|) -> ws[0] as uint bits (all values >= 0
// in practice; use unsigned compare of IEEE bits which is monotone for >=0).
// ---------------------------------------------------------------------------
__global__ __launch_bounds__(256)
void maxred_kernel(const float* __restrict__ wp, const float* __restrict__ wn,
                   const float* __restrict__ bp, const float* __restrict__ bn,
                   unsigned* __restrict__ out)
{
    const int idx    = blockIdx.x * blockDim.x + threadIdx.x;
    const int stride = gridDim.x * blockDim.x;
    const int NW = N_IN * N_OUT;
    float m = 0.0f;
    for (int i = idx; i < NW; i += stride) {
        m = fmaxf(m, fabsf(wp[i]));
        m = fmaxf(m, fabsf(wn[i]));
    }
    if (idx < N_OUT) {
        m = fmaxf(m, fabsf(bp[idx]));
        m = fmaxf(m, fabsf(bn[idx]));
    }
    // wave-64 butterfly reduce
    #pragma unroll
    for (int off = 32; off > 0; off >>= 1)
        m = fmaxf(m, __shfl_xor(m, off, 64));
    if ((threadIdx.x & 63) == 0)
        atomicMax(out, __float_as_uint(m));
}

// ---------------------------------------------------------------------------
// Kernel 2: main crossbar compute.
//   y[b,j] = sum_i s[b,i] * ( gp[i,j]*exp2(ep[i,j]*l[b,i])
//                           - gn[i,j]*exp2(en[i,j]*l[b,i]) )
//   g = 0.5*w + 0.125*max_w ; e = log2(2.8 + 0.2*noise) ; l = log2(2|x|)
// Block: 256 thr = 64 j-lanes x 4 waves; each wave owns 8 batches (BB acc).
// Grid:  J_TILES * B_TILES * I_CHUNKS blocks; partials via atomicAdd.
// ---------------------------------------------------------------------------
__global__ __launch_bounds__(256)
void memristor_kernel(const float* __restrict__ x,  const float* __restrict__ wp,
                      const float* __restrict__ wn, const float* __restrict__ bp,
                      const float* __restrict__ bn, const float* __restrict__ nn,
                      const unsigned* __restrict__ maxw_bits,
                      float* __restrict__ y)
{
    __shared__ float2 lsbuf[BT][CH];   // (l = log2(2|x|), s = sign(x)) per (batch, row)

    const int jlane = threadIdx.x & 63;
    const int bslot = threadIdx.x >> 6;      // 0..3

    int bid = blockIdx.x;
    const int jt = bid & (J_TILES - 1);  bid >>= 3;   // 8 j tiles
    const int bt = bid & (B_TILES - 1);  bid >>= 2;   // 4 b tiles
    const int ic = bid;                               // 16 i chunks

    const int j0 = jt * JT;
    const int b0 = bt * BT;
    const int i0 = ic * CH;
    const int iend = min(i0 + CH, N_IN + 1);

    // ---- stage (l, s) for this block's batches / row-chunk ----
    for (int idx = threadIdx.x; idx < BT * CH; idx += 256) {
        const int bb = idx / CH;
        const int ii = idx - bb * CH;
        const int i  = i0 + ii;
        float l, s;
        if (i < N_IN) {
            const float v = x[(b0 + bb) * N_IN + i];
            s = (v > 0.0f) ? 1.0f : ((v < 0.0f) ? -1.0f : 0.0f);
            l = FAST_LOG2(2.0f * fabsf(v));    // -inf when v==0: exp2 -> 0, s==0
        } else {                               // bias word line (i == N_IN)
            s = 1.0f;
            l = 1.0f;                          // ratio = 2
        }
        lsbuf[bb][ii] = make_float2(l, s);
    }
    __syncthreads();

    const float maxw = __uint_as_float(*maxw_bits);
    const float gofs = 0.125f * maxw;
    const int   j    = j0 + jlane;

    float acc[BB];
    #pragma unroll
    for (int k = 0; k < BB; ++k) acc[k] = 0.0f;

    for (int i = i0; i < iend; ++i) {
        float wpv, wnv;
        if (i < N_IN) {
            wpv = wp[i * N_OUT + j];
            wnv = wn[i * N_OUT + j];
        } else {
            wpv = bp[j];
            wnv = bn[j];
        }
        const float2 np2 = *reinterpret_cast<const float2*>(&nn[i * (2 * N_OUT) + 2 * j]);
        const float ep = FAST_LOG2(fmaf(0.2f, np2.x, 2.8f));
        const float en = FAST_LOG2(fmaf(0.2f, np2.y, 2.8f));
        const float gp = fmaf(0.5f, wpv, gofs);
        const float gn = fmaf(0.5f, wnv, gofs);
        const int   ii = i - i0;

        #pragma unroll
        for (int k = 0; k < BB; ++k) {
            const float2 lsv = lsbuf[bslot * BB + k][ii];   // wave-uniform broadcast
            const float Ep = FAST_EXP2(ep * lsv.x);
            const float En = FAST_EXP2(en * lsv.x);
            const float t  = fmaf(gp, Ep, -(gn * En));
            acc[k] = fmaf(lsv.y, t, acc[k]);
        }
    }

    #pragma unroll
    for (int k = 0; k < BB; ++k) {
        atomicAdd(&y[(b0 + bslot * BB + k) * N_OUT + j], acc[k]);
    }
}

// ---------------------------------------------------------------------------
extern "C" void kernel_launch(void* const* d_in, const int* in_sizes, int n_in,
                              void* d_out, int out_size, void* d_ws, size_t ws_size,
                              hipStream_t stream)
{
    const float* x  = (const float*)d_in[0];
    const float* wp = (const float*)d_in[1];
    const float* wn = (const float*)d_in[2];
    const float* bp = (const float*)d_in[3];
    const float* bn = (const float*)d_in[4];
    const float* nn = (const float*)d_in[5];
    float*    y     = (float*)d_out;
    unsigned* wsmax = (unsigned*)d_ws;

    // zero the max-reduction slot and the (atomicAdd-accumulated) output
    (void)hipMemsetAsync(wsmax, 0, sizeof(unsigned), stream);
    (void)hipMemsetAsync(y, 0, (size_t)out_size * sizeof(float), stream);

    maxred_kernel<<<256, 256, 0, stream>>>(wp, wn, bp, bn, wsmax);

    const int nblocks = J_TILES * B_TILES * I_CHUNKS;   // 512
    memristor_kernel<<<nblocks, 256, 0, stream>>>(x, wp, wn, bp, bn, nn, wsmax, y);
}